// Round 5
// baseline (285.173 us; speedup 1.0000x reference)
//
#include <hip/hip_runtime.h>

// ---------------------------------------------------------------------------
// LocalWindowAttentionLayer on MI355X (gfx950)
// B=4 L=2048 D=512 H=8 DK=64 DF=2048 W=9
//
// Pipeline (G2 folded into G1 via Wvo = Wv@Wo):
//  prep: fused transpose weights -> bf16 [N][K]; bias prep (bq,bk,bvo=bv@Wo,0)
//  W  : WvoT = (Wv@Wo)^T  (tiny bf16 GEMM)
//  G1 : QKV'' = xb @ [Wq;Wk;Wvo]^T + [bq;bk;bvo]   (8192 x 1536, K=512)
//  A  : banded-Gram attention -> newx = sum_kw wbar*V'' + bo  (8192 x 512)
//  LN1: x1 = LN(xb + newx)
//  G3 : h = gelu(x1 @ W1T^T + b1)       (8192 x 2048, K=512)
//  G4 : y = h @ W2T^T + b2              (8192 x 512,  K=2048)
//  LN2: out = LN(x1 + y) -> fp32
//
// GEMM structure (R5): NO LDS, NO barriers. Weights are L2-resident
// (1.5-2 MB), activations L3-resident; each wave loads its MFMA fragments
// directly from global (64B-coalesced per 4 lanes), compiler pipelines
// freely. XCD-chunked block swizzle (T1) kept.
// ---------------------------------------------------------------------------

typedef unsigned short u16;
typedef __attribute__((ext_vector_type(8))) short short8;   // 8 bf16
typedef __attribute__((ext_vector_type(4))) float floatx4;  // MFMA acc

#define DEV static __device__ __forceinline__

DEV float b2f(u16 u) {
  union { unsigned int i; float f; } x; x.i = ((unsigned int)u) << 16; return x.f;
}
DEV u16 f2b(float f) {  // round-to-nearest-even
  union { float f; unsigned int i; } x; x.f = f;
  unsigned int u = x.i + 0x7fffu + ((x.i >> 16) & 1u);
  return (u16)(u >> 16);
}

// ---------------------------------------------------------------------------
// Fused weight prep: transposes (fp32 RxC -> bf16 CxR) for Wq,Wk,Wo,W1,W2
// plus straight f2b copy of Wv. One launch.
// ---------------------------------------------------------------------------
__global__ __launch_bounds__(256) void prep_weights(
    const float* __restrict__ Wq, const float* __restrict__ Wk,
    const float* __restrict__ Wo, const float* __restrict__ W1,
    const float* __restrict__ W2, const float* __restrict__ Wv,
    u16* __restrict__ WqkvT, u16* __restrict__ WoT,
    u16* __restrict__ W1T, u16* __restrict__ W2T, u16* __restrict__ Wvb) {
  const int bid = blockIdx.x;
  if (bid >= 2816) {  // Wv f2b copy (512x512)
    const int i = (bid - 2816) * 256 + threadIdx.x;
    float4 v = ((const float4*)Wv)[i];
    ushort4 o;
    o.x = f2b(v.x); o.y = f2b(v.y); o.z = f2b(v.z); o.w = f2b(v.w);
    ((ushort4*)Wvb)[i] = o;
    return;
  }
  const float* in; u16* out; int R, C, t;
  if (bid < 256)       { in = Wq; out = WqkvT;          R = 512;  C = 512;  t = bid; }
  else if (bid < 512)  { in = Wk; out = WqkvT + 262144; R = 512;  C = 512;  t = bid - 256; }
  else if (bid < 768)  { in = Wo; out = WoT;            R = 512;  C = 512;  t = bid - 512; }
  else if (bid < 1792) { in = W1; out = W1T;            R = 512;  C = 2048; t = bid - 768; }
  else                 { in = W2; out = W2T;            R = 2048; C = 512;  t = bid - 1792; }
  const int tpr = C >> 5;
  const int bc = (t % tpr) * 32, br = (t / tpr) * 32;
  __shared__ float tile[32][33];
  const int tx = threadIdx.x & 31, ty = threadIdx.x >> 5;
  #pragma unroll
  for (int i = 0; i < 32; i += 8)
    tile[ty + i][tx] = in[(size_t)(br + ty + i) * C + bc + tx];
  __syncthreads();
  #pragma unroll
  for (int i = 0; i < 32; i += 8)
    out[(size_t)(bc + ty + i) * R + br + tx] = f2b(tile[tx][ty + i]);
}

// bqkv[0:512)=bq, [512:1024)=bk, [1024:1536)=bvo=bv@Wo, [1536:2048)=0
__global__ __launch_bounds__(256) void bias_prep(
    const float* __restrict__ bq, const float* __restrict__ bk,
    const float* __restrict__ bv, const float* __restrict__ Wo,
    float* __restrict__ o) {
  const int i = blockIdx.x * 256 + threadIdx.x;
  if (i < 512) o[i] = bq[i];
  else if (i < 1024) o[i] = bk[i - 512];
  else if (i < 1536) {
    const int c = i - 1024;
    float s = 0.f;
    for (int j = 0; j < 512; ++j) s += bv[j] * Wo[(size_t)j * 512 + c];
    o[i] = s;
  } else if (i < 2048) o[i] = 0.f;
}

__global__ __launch_bounds__(256) void f2b_vec(
    const float* __restrict__ in, u16* __restrict__ out, int n4) {
  int i = blockIdx.x * 256 + threadIdx.x;
  if (i < n4) {
    float4 v = ((const float4*)in)[i];
    ushort4 o;
    o.x = f2b(v.x); o.y = f2b(v.y); o.z = f2b(v.z); o.w = f2b(v.w);
    ((ushort4*)out)[i] = o;
  }
}

// ---------------------------------------------------------------------------
// Direct-from-global bf16 MFMA GEMM (no LDS, no barriers).
// C[M][N] = A[M][K] @ BT[N][K]^T + bias ; EPI: 0=bias, 1=bias+gelu
// BM=BN=128, 256 thr = 4 waves (2x2), wave 64x64 = 4x4 frags of 16x16x32.
// Fragment loads: lane (l4,l15) reads A[bm+wm+i*16+l15][k+l4*8 ..+8] (16B);
// the 4 l4-lanes of one row cover 64B contiguous -> fully coalesced.
// Weights (BT) are L2-resident; activations L3-resident.
// ---------------------------------------------------------------------------
template<int EPI>
__global__ __launch_bounds__(256, 4) void gemm_direct(
    const u16* __restrict__ A, const u16* __restrict__ BT,
    const float* __restrict__ bias, u16* __restrict__ C,
    int M, int N, int K) {
  const int tid  = threadIdx.x;
  const int wave = tid >> 6, lane = tid & 63;
  const int l15 = lane & 15, l4 = lane >> 4;

  // T1: XCD-chunked swizzle (all grids %8==0): same-panel blocks share an L2.
  const int gx = (int)gridDim.x;
  const int nwg = gx * (int)gridDim.y;
  int id = (int)blockIdx.y * gx + (int)blockIdx.x;
  const int cpx = nwg >> 3;
  id = (id & 7) * cpx + (id >> 3);
  const int bn = (id % gx) * 128;
  const int bm = (id / gx) * 128;
  const int wm = (wave >> 1) * 64, wn = (wave & 1) * 64;

  floatx4 acc[4][4] = {};

  const u16* pa = A  + (size_t)(bm + wm + l15) * K + l4 * 8;
  const u16* pb = BT + (size_t)(bn + wn + l15) * K + l4 * 8;
  const size_t rs = (size_t)16 * K;  // fragment row stride

  #pragma unroll 2
  for (int k = 0; k < K; k += 32) {
    short8 af[4], bf4[4];
    #pragma unroll
    for (int i = 0; i < 4; ++i) {
      af[i]  = *(const short8*)(pa + i * rs + k);
      bf4[i] = *(const short8*)(pb + i * rs + k);
    }
    #pragma unroll
    for (int i = 0; i < 4; ++i)
      #pragma unroll
      for (int j = 0; j < 4; ++j)
        acc[i][j] = __builtin_amdgcn_mfma_f32_16x16x32_bf16(af[i], bf4[j], acc[i][j], 0, 0, 0);
  }

  float bvv[4];
  #pragma unroll
  for (int j = 0; j < 4; ++j) bvv[j] = bias[bn + wn + j * 16 + l15];
  #pragma unroll
  for (int i = 0; i < 4; ++i) {
    #pragma unroll
    for (int r = 0; r < 4; ++r) {
      size_t row = (size_t)(bm + wm + i * 16 + l4 * 4 + r);
      u16* cp = C + row * N + (bn + wn + l15);
      #pragma unroll
      for (int j = 0; j < 4; ++j) {
        float vv = acc[i][j][r] + bvv[j];
        if (EPI == 1) vv = 0.5f * vv * (1.0f + erff(vv * 0.70710678118654752f));
        cp[j * 16] = f2b(vv);
      }
    }
  }
}

// ---------------------------------------------------------------------------
// Banded-Gram attention. One block per (b, 32-pos chunk, head).
// V here is V'' = win @ Wvo + bvo, so output is newx directly (+bo).
// ---------------------------------------------------------------------------
#define ATL 32
#define ART (ATL + 8)   // 40 staged rows

__global__ __launch_bounds__(256) void attn_band(
    const u16* __restrict__ QKV, const float* __restrict__ bqkv,
    const float* __restrict__ bo, u16* __restrict__ newx) {
  __shared__ __align__(16) u16 S3[3][ART][72];
  __shared__ float Gb[ART][18];
  __shared__ float Sm[ART][81];
  __shared__ float Wb[ATL][9];

  const int tid = threadIdx.x;
  const int bid = ((int)blockIdx.x & 7) * 256 + ((int)blockIdx.x >> 3);
  const int h = bid & 7;
  const int chunk = (bid >> 3) & 63;
  const int b = bid >> 9;
  const int l0 = chunk * ATL;

  for (int idx = tid; idx < ART * 24; idx += 256) {
    const int ti = idx / 24, c = idx % 24;
    const int slice = c >> 3, d8 = (c & 7) * 8;
    const int col = slice * 512 + h * 64 + d8;
    const int t = l0 - 4 + ti;
    short8 v;
    if ((unsigned)t < 2048u) {
      v = *(const short8*)(QKV + ((size_t)((b << 11) | t)) * 1536 + col);
    } else {
      #pragma unroll
      for (int j = 0; j < 8; ++j) v[j] = (short)f2b(bqkv[col + j]);
    }
    *(short8*)(&S3[slice][ti][d8]) = v;
  }
  __syncthreads();

  for (int task = tid; task < ART * 17; task += 256) {
    const int ti = task / 17, j = task % 17;
    const int ui = ti + j - 8;
    if ((unsigned)ui < (unsigned)ART) {
      float a = 0.f;
      #pragma unroll
      for (int d0 = 0; d0 < 64; d0 += 8) {
        short8 qv = *(const short8*)(&S3[0][ti][d0]);
        short8 kv = *(const short8*)(&S3[1][ui][d0]);
        #pragma unroll
        for (int jj = 0; jj < 8; ++jj) a += b2f((u16)qv[jj]) * b2f((u16)kv[jj]);
      }
      Gb[ti][j] = a * 0.125f;
    }
  }
  __syncthreads();

  for (int task = tid; task < ART * 9; task += 256) {
    const int ti = task / 9, qw = task % 9;
    const int li = ti - qw;
    if ((unsigned)li < (unsigned)ATL) {
      float m = -1e30f;
      #pragma unroll
      for (int kw = 0; kw < 9; ++kw) m = fmaxf(m, Gb[ti][kw - qw + 8]);
      float e[9], s = 0.f;
      #pragma unroll
      for (int kw = 0; kw < 9; ++kw) { e[kw] = expf(Gb[ti][kw - qw + 8] - m); s += e[kw]; }
      const float inv = 1.f / s;
      #pragma unroll
      for (int kw = 0; kw < 9; ++kw) Sm[ti][qw * 9 + kw] = e[kw] * inv;
    }
  }
  __syncthreads();

  for (int task = tid; task < ATL * 9; task += 256) {
    const int li = task / 9, kw = task % 9;
    float s = 0.f;
    #pragma unroll
    for (int qw = 0; qw < 9; ++qw) s += Sm[li + qw][qw * 9 + kw];
    Wb[li][kw] = s * (1.f / 9.f);
  }
  __syncthreads();

  {
    const int li = tid >> 3, d8 = (tid & 7) * 8;
    float w[9];
    #pragma unroll
    for (int kw = 0; kw < 9; ++kw) w[kw] = Wb[li][kw];
    float a[8] = {};
    #pragma unroll
    for (int kw = 0; kw < 9; ++kw) {
      short8 vv = *(const short8*)(&S3[2][li + kw][d8]);
      #pragma unroll
      for (int jj = 0; jj < 8; ++jj) a[jj] += w[kw] * b2f((u16)vv[jj]);
    }
    short8 o;
    #pragma unroll
    for (int jj = 0; jj < 8; ++jj) o[jj] = (short)f2b(a[jj] + bo[h * 64 + d8 + jj]);
    const int l = l0 + li;
    *(short8*)(newx + ((size_t)((b << 11) | l)) * 512 + h * 64 + d8) = o;
  }
}

// ---------------------------------------------------------------------------
// LayerNorm over D=512: v = a(bf16) + b(bf16). One wave per row, 4 rows/block.
// OUTF=0 -> bf16 out; OUTF=1 -> fp32 out.
// ---------------------------------------------------------------------------
template<int OUTF>
__global__ __launch_bounds__(256) void ln_kernel(
    const u16* __restrict__ a, const u16* __restrict__ bsrc,
    const float* __restrict__ g, const float* __restrict__ be,
    u16* __restrict__ outb, float* __restrict__ outf) {
  const int wave = threadIdx.x >> 6, lane = threadIdx.x & 63;
  const size_t row = (size_t)blockIdx.x * 4 + wave;
  const size_t base = row * 512 + lane * 8;
  const int gi = lane * 8;
  float v[8];
  short8 a8 = *(const short8*)(a + base);
  short8 b8 = *(const short8*)(bsrc + base);
  #pragma unroll
  for (int j = 0; j < 8; ++j) v[j] = b2f((u16)a8[j]) + b2f((u16)b8[j]);

  float s = 0.f;
  #pragma unroll
  for (int j = 0; j < 8; ++j) s += v[j];
  #pragma unroll
  for (int off = 32; off >= 1; off >>= 1) s += __shfl_xor(s, off, 64);
  const float mean = s * (1.f / 512.f);
  float sq = 0.f;
  #pragma unroll
  for (int j = 0; j < 8; ++j) { float d = v[j] - mean; sq += d * d; }
  #pragma unroll
  for (int off = 32; off >= 1; off >>= 1) sq += __shfl_xor(sq, off, 64);
  const float rs = rsqrtf(sq * (1.f / 512.f) + 1e-5f);

  if (OUTF == 0) {
    short8 o;
    #pragma unroll
    for (int j = 0; j < 8; ++j)
      o[j] = (short)f2b((v[j] - mean) * rs * g[gi + j] + be[gi + j]);
    *(short8*)(outb + base) = o;
  } else {
    float4 o0, o1;
    o0.x = (v[0] - mean) * rs * g[gi + 0] + be[gi + 0];
    o0.y = (v[1] - mean) * rs * g[gi + 1] + be[gi + 1];
    o0.z = (v[2] - mean) * rs * g[gi + 2] + be[gi + 2];
    o0.w = (v[3] - mean) * rs * g[gi + 3] + be[gi + 3];
    o1.x = (v[4] - mean) * rs * g[gi + 4] + be[gi + 4];
    o1.y = (v[5] - mean) * rs * g[gi + 5] + be[gi + 5];
    o1.z = (v[6] - mean) * rs * g[gi + 6] + be[gi + 6];
    o1.w = (v[7] - mean) * rs * g[gi + 7] + be[gi + 7];
    *(float4*)(outf + base) = o0;
    *(float4*)(outf + base + 4) = o1;
  }
}

// ---------------------------------------------------------------------------
extern "C" void kernel_launch(void* const* d_in, const int* in_sizes, int n_in,
                              void* d_out, int out_size, void* d_ws, size_t ws_size,
                              hipStream_t stream) {
  const float* x   = (const float*)d_in[0];
  const float* Wq  = (const float*)d_in[1];
  const float* bq  = (const float*)d_in[2];
  const float* Wk  = (const float*)d_in[3];
  const float* bk  = (const float*)d_in[4];
  const float* Wv  = (const float*)d_in[5];
  const float* bv  = (const float*)d_in[6];
  const float* Wo  = (const float*)d_in[7];
  const float* bo  = (const float*)d_in[8];
  const float* W1  = (const float*)d_in[9];
  const float* b1  = (const float*)d_in[10];
  const float* W2  = (const float*)d_in[11];
  const float* b2  = (const float*)d_in[12];
  const float* g1  = (const float*)d_in[13];
  const float* be1 = (const float*)d_in[14];
  const float* g2  = (const float*)d_in[15];
  const float* be2 = (const float*)d_in[16];

  char* w = (char*)d_ws;
  u16*   xb    = (u16*)  (w + 0);           // 8 MB
  u16*   WqkvT = (u16*)  (w + 8388608);     // [1536][512] bf16 (q,k,vo)
  u16*   WoT   = (u16*)  (w + 9961472);     // [512][512]
  u16*   W1T   = (u16*)  (w + 10485760);    // [2048][512]
  u16*   W2T   = (u16*)  (w + 12582912);    // [512][2048]
  float* bqkv  = (float*)(w + 14680064);    // 2048 f32 (bq,bk,bvo,zeros)
  u16*   Wvb   = (u16*)  (w + 14688256);    // [512][512] bf16 row-major Wv
  u16*   QKV   = (u16*)  (w + 15212544);    // 8192x1536 bf16 (dead after attn)
  u16*   hbuf  = QKV;                       // 8192x2048 bf16 (aliases QKV)
  u16*   newx  = (u16*)  (w + 48766976);    // 8192x512 bf16 (dead after LN1)
  u16*   ybuf  = newx;                      // 8192x512 bf16 (aliases newx)
  u16*   x1b   = (u16*)  (w + 57155584);    // 8192x512 bf16
  u16*   WvoT  = WqkvT + 524288;            // V region of WqkvT = (Wv@Wo)^T

  // --- prep ---
  prep_weights<<<3072, 256, 0, stream>>>(Wq, Wk, Wo, W1, W2, Wv,
                                         WqkvT, WoT, W1T, W2T, Wvb);
  bias_prep<<<8, 256, 0, stream>>>(bq, bk, bv, Wo, bqkv);
  f2b_vec<<<4096, 256, 0, stream>>>(x, xb, 1048576);
  // --- WvoT = (Wv@Wo)^T : C[m][n] = sum_j WoT[m][j]*Wvb[n][j] = Wvo[n][m] ---
  gemm_direct<0><<<dim3(4, 4), 256, 0, stream>>>(WoT, Wvb, bqkv + 1536, WvoT, 512, 512, 512);
  // --- G1: QKV'' ---
  gemm_direct<0><<<dim3(12, 64), 256, 0, stream>>>(xb, WqkvT, bqkv, QKV, 8192, 1536, 512);
  // --- attention (banded Gram) -> newx ---
  attn_band<<<2048, 256, 0, stream>>>(QKV, bqkv, bo, newx);
  // --- LN1 (bf16 x + bf16 newx) ---
  ln_kernel<0><<<2048, 256, 0, stream>>>(xb, newx, g1, be1, x1b, nullptr);
  // --- G3: W1 + gelu ---
  gemm_direct<1><<<dim3(16, 64), 256, 0, stream>>>(x1b, W1T, b1, hbuf, 8192, 2048, 512);
  // --- G4: W2 ---
  gemm_direct<0><<<dim3(4, 64), 256, 0, stream>>>(hbuf, W2T, b2, ybuf, 8192, 512, 2048);
  // --- LN2 -> out ---
  ln_kernel<1><<<2048, 256, 0, stream>>>(x1b, ybuf, g2, be2, nullptr, (float*)d_out);
}

// Round 6
// 205.472 us; speedup vs baseline: 1.3879x; 1.3879x over previous
//
#include <hip/hip_runtime.h>

// ---------------------------------------------------------------------------
// LocalWindowAttentionLayer on MI355X (gfx950)
// B=4 L=2048 D=512 H=8 DK=64 DF=2048 W=9
//
// Pipeline (G2 folded into G1 via Wvo = Wv@Wo):
//  prep: transpose weights -> bf16 [N][K]; bias prep; Wvo via fp32 tile GEMM
//  G1 : QKV'' = xb @ [Wq;Wk;Wvo]^T + [bq;bk;bvo]   (8192 x 1536, K=512)
//  A  : banded-Gram attention -> newx (8192 x 512)
//  LN1: x1 = LN(xb + newx)
//  G3 : h = gelu(x1 @ W1T^T + b1)       (8192 x 2048, K=512)
//  G4 : y = h @ W2T^T  (split-K=2 -> 2 bf16 partials)
//  LN2: out = LN(x1 + y0 + y1 + b2) -> fp32
//
// gemm_big (R6): BM=BN=256, BK=32, 512 thr = 8 waves (2Mx4N, wave 128x64).
// 4 LDS K-tile buffers (128 KB), lookahead-2 pipeline, counted vmcnt(4)
// (never 0 in steady state), granule-XOR LDS swizzle (conflict-free reads,
// inverse applied on global source - rule #21), setprio around MFMA clusters,
// XCD-chunked block swizzle.
// ---------------------------------------------------------------------------

typedef unsigned short u16;
typedef __attribute__((ext_vector_type(8))) short short8;   // 8 bf16
typedef __attribute__((ext_vector_type(4))) float floatx4;  // MFMA acc

#define DEV static __device__ __forceinline__

DEV float b2f(u16 u) {
  union { unsigned int i; float f; } x; x.i = ((unsigned int)u) << 16; return x.f;
}
DEV u16 f2b(float f) {  // round-to-nearest-even
  union { float f; unsigned int i; } x; x.f = f;
  unsigned int u = x.i + 0x7fffu + ((x.i >> 16) & 1u);
  return (u16)(u >> 16);
}

#define AS1 __attribute__((address_space(1)))
#define AS3 __attribute__((address_space(3)))
DEV void gload_lds16(const void* g, void* l) {
  __builtin_amdgcn_global_load_lds((const AS1 void*)g, (AS3 void*)l, 16, 0, 0);
}

// ---------------------------------------------------------------------------
// Fused weight prep: transposes (fp32 RxC -> bf16 CxR) for Wq,Wk,Wo,W1,W2
// plus f2b copy of Wv. (WoT/Wvb legacy, harmless.)
// ---------------------------------------------------------------------------
__global__ __launch_bounds__(256) void prep_weights(
    const float* __restrict__ Wq, const float* __restrict__ Wk,
    const float* __restrict__ Wo, const float* __restrict__ W1,
    const float* __restrict__ W2, const float* __restrict__ Wv,
    u16* __restrict__ WqkvT, u16* __restrict__ WoT,
    u16* __restrict__ W1T, u16* __restrict__ W2T, u16* __restrict__ Wvb) {
  const int bid = blockIdx.x;
  if (bid >= 2816) {  // Wv f2b copy (512x512)
    const int i = (bid - 2816) * 256 + threadIdx.x;
    float4 v = ((const float4*)Wv)[i];
    ushort4 o;
    o.x = f2b(v.x); o.y = f2b(v.y); o.z = f2b(v.z); o.w = f2b(v.w);
    ((ushort4*)Wvb)[i] = o;
    return;
  }
  const float* in; u16* out; int R, C, t;
  if (bid < 256)       { in = Wq; out = WqkvT;          R = 512;  C = 512;  t = bid; }
  else if (bid < 512)  { in = Wk; out = WqkvT + 262144; R = 512;  C = 512;  t = bid - 256; }
  else if (bid < 768)  { in = Wo; out = WoT;            R = 512;  C = 512;  t = bid - 512; }
  else if (bid < 1792) { in = W1; out = W1T;            R = 512;  C = 2048; t = bid - 768; }
  else                 { in = W2; out = W2T;            R = 2048; C = 512;  t = bid - 1792; }
  const int tpr = C >> 5;
  const int bc = (t % tpr) * 32, br = (t / tpr) * 32;
  __shared__ float tile[32][33];
  const int tx = threadIdx.x & 31, ty = threadIdx.x >> 5;
  #pragma unroll
  for (int i = 0; i < 32; i += 8)
    tile[ty + i][tx] = in[(size_t)(br + ty + i) * C + bc + tx];
  __syncthreads();
  #pragma unroll
  for (int i = 0; i < 32; i += 8)
    out[(size_t)(bc + ty + i) * R + br + tx] = f2b(tile[tx][ty + i]);
}

// bqkv[0:512)=bq, [512:1024)=bk, [1536:2048)=0.  ([1024:1536)=bvo from wvo_kernel)
__global__ __launch_bounds__(256) void bias_prep(
    const float* __restrict__ bq, const float* __restrict__ bk,
    float* __restrict__ o) {
  const int i = blockIdx.x * 256 + threadIdx.x;
  if (i < 512) o[i] = bq[i];
  else if (i < 1024) o[i] = bk[i - 512];
  else if (i >= 1536 && i < 2048) o[i] = 0.f;
}

// ---------------------------------------------------------------------------
// Wvo = Wv@Wo (fp32 in, bf16 out, transposed): WvoT[n][k] = sum_j Wv[k][j]Wo[j][n]
// Also bvo[n] = sum_j bv[j]*Wo[j][n] (blocks with tk==0).
// grid (tn, tk) 8x8, 64x64 output tiles, 256 threads -> 4x4 outputs each.
// ---------------------------------------------------------------------------
__global__ __launch_bounds__(256) void wvo_kernel(
    const float* __restrict__ Wv, const float* __restrict__ Wo,
    const float* __restrict__ bv,
    u16* __restrict__ WvoT, float* __restrict__ bvo) {
  __shared__ float Vs[64][65];
  __shared__ float Os[64][65];
  const int tn = blockIdx.x, tk = blockIdx.y;
  const int tid = threadIdx.x;
  const int tx = tid & 15, ty = tid >> 4;
  const int k0 = tk * 64, n0 = tn * 64;
  float acc[4][4] = {};
  float bacc = 0.f;
  for (int j0 = 0; j0 < 512; j0 += 64) {
    for (int i = tid; i < 64 * 64; i += 256) {
      const int r = i >> 6, c = i & 63;
      Vs[r][c] = Wv[(size_t)(k0 + r) * 512 + j0 + c];
      Os[r][c] = Wo[(size_t)(j0 + r) * 512 + n0 + c];
    }
    __syncthreads();
    #pragma unroll 4
    for (int j = 0; j < 64; ++j) {
      float vv[4], ov[4];
      #pragma unroll
      for (int a = 0; a < 4; ++a) vv[a] = Vs[ty * 4 + a][j];
      #pragma unroll
      for (int b = 0; b < 4; ++b) ov[b] = Os[j][tx * 4 + b];
      #pragma unroll
      for (int a = 0; a < 4; ++a)
        #pragma unroll
        for (int b = 0; b < 4; ++b) acc[a][b] += vv[a] * ov[b];
    }
    if (tk == 0 && tid < 64) {
      float s = 0.f;
      for (int jj = 0; jj < 64; ++jj) s += bv[j0 + jj] * Os[jj][tid];
      bacc += s;
    }
    __syncthreads();
  }
  #pragma unroll
  for (int a = 0; a < 4; ++a)
    #pragma unroll
    for (int b = 0; b < 4; ++b)
      WvoT[(size_t)(n0 + tx * 4 + b) * 512 + k0 + ty * 4 + a] = f2b(acc[a][b]);
  if (tk == 0 && tid < 64) bvo[n0 + tid] = bacc;
}

__global__ __launch_bounds__(256) void f2b_vec(
    const float* __restrict__ in, u16* __restrict__ out, int n4) {
  int i = blockIdx.x * 256 + threadIdx.x;
  if (i < n4) {
    float4 v = ((const float4*)in)[i];
    ushort4 o;
    o.x = f2b(v.x); o.y = f2b(v.y); o.z = f2b(v.z); o.w = f2b(v.w);
    ((ushort4*)out)[i] = o;
  }
}

// ---------------------------------------------------------------------------
// Deep-pipelined bf16 MFMA GEMM.  C = A[M][lda-slice] @ BT[N][..]^T (+ bias)
// EPI: 0=bias->bf16, 1=bias+gelu->bf16, 2=raw bf16 partial (split-K via z)
// Geometry: BM=BN=256, BK=32, 512 threads, 8 waves (wr=w>>2 in{0,1}, wc=w&3),
// wave tile 128x64 -> acc[8][4] 16x16 frags. 4 LDS K-tile buffers, 32KB each.
//
// LDS swizzle: physical granule = logical granule ^ s(row), s(r)=(r&3)^((r>>2)&3).
// Staging keeps the LDS dest LINEAR (global_load_lds constraint) and applies
// the (involutive) permutation to the per-lane GLOBAL source granule; the
// fragment read applies the same XOR -> 2-way bank aliasing only (free).
// Pipeline: lookahead 2 K-tiles; per iter issue 4 loads (A then B of kt+2)
// inside the two MFMA phases; end with s_waitcnt vmcnt(4) (counted!) + barrier.
// ---------------------------------------------------------------------------
template<int EPI>
__global__ __launch_bounds__(512, 2) void gemm_big(
    const u16* __restrict__ A, const u16* __restrict__ BT,
    const float* __restrict__ bias, u16* __restrict__ C, u16* __restrict__ C2,
    int M, int N, int lda, int kb) {
  __shared__ __align__(16) u16 L[4][16384];   // 4 x (A 256x32 | B 256x32) = 128KB
  const int tid = threadIdx.x;
  const int w = tid >> 6, l = tid & 63;
  const int l15 = l & 15, l4 = l >> 4;
  const int wr = w >> 2, wc = w & 3;

  // T1: XCD-chunked swizzle over the flattened 3D grid (guard nwg%8).
  const int gx = (int)gridDim.x, gy = (int)gridDim.y;
  int id = ((int)blockIdx.z * gy + (int)blockIdx.y) * gx + (int)blockIdx.x;
  const int nwg = gx * gy * (int)gridDim.z;
  if ((nwg & 7) == 0) { const int cpx = nwg >> 3; id = (id & 7) * cpx + (id >> 3); }
  const int bx = id % gx; const int r1 = id / gx;
  const int by = r1 % gy; const int bz = r1 / gy;
  const int bm = by * 256, bn = bx * 256;
  const int koff = bz * kb;

  // staging addresses: lane-constant swizzled source granule
  const int srcg8 = ((l & 3) ^ ((l >> 2) & 3) ^ ((l >> 4) & 3)) * 8;
  const int srow = w * 16 + (l >> 2);          // row within 128-row pass block
  const u16* gA = A  + (size_t)(bm + srow) * lda + koff + srcg8;
  const u16* gB = BT + (size_t)(bn + srow) * lda + koff + srcg8;
  const size_t p1a = (size_t)128 * lda;        // pass-1 row offset
  const int sdst = w * 512 + l * 8;            // linear LDS dest (elements)

  // fragment read offsets: physical granule = l4 ^ s(l15)
  const int rg8 = (l4 ^ (l15 & 3) ^ ((l15 >> 2) & 3)) * 8;
  const int aBase = (wr * 128 + l15) * 32 + rg8;
  const int bBase = 8192 + (wc * 64 + l15) * 32 + rg8;

  floatx4 acc[8][4] = {};
  const int nt = kb >> 5;

  // prologue: stage kt=0 and kt=1 (8 loads), wait for kt0 (4 left in flight)
  gload_lds16(gA,            &L[0][sdst]);
  gload_lds16(gA + p1a,      &L[0][4096 + sdst]);
  gload_lds16(gB,            &L[0][8192 + sdst]);
  gload_lds16(gB + p1a,      &L[0][12288 + sdst]);
  gload_lds16(gA + 32,       &L[1][sdst]);
  gload_lds16(gA + p1a + 32, &L[1][4096 + sdst]);
  gload_lds16(gB + 32,       &L[1][8192 + sdst]);
  gload_lds16(gB + p1a + 32, &L[1][12288 + sdst]);
  asm volatile("s_waitcnt vmcnt(4)" ::: "memory");
  __builtin_amdgcn_s_barrier();
  asm volatile("" ::: "memory");

  for (int kt = 0; kt < nt; ++kt) {
    const u16* Lb = &L[kt & 3][0];
    const bool pf = (kt + 2 < nt);
    u16* Ln = &L[(kt + 2) & 3][0];
    const u16* ga = gA + (size_t)(kt + 2) * 32;
    const u16* gb = gB + (size_t)(kt + 2) * 32;

    // ---- phase 0: issue A-stage(kt+2) ; A m0-3 + B n0-3 ; 16 MFMA ----
    if (pf) {
      gload_lds16(ga,       Ln + sdst);
      gload_lds16(ga + p1a, Ln + 4096 + sdst);
    }
    short8 a0[4], bf[4];
    #pragma unroll
    for (int m = 0; m < 4; ++m) a0[m] = *(const short8*)(Lb + aBase + m * 512);
    #pragma unroll
    for (int n = 0; n < 4; ++n) bf[n] = *(const short8*)(Lb + bBase + n * 512);
    __builtin_amdgcn_s_setprio(1);
    #pragma unroll
    for (int m = 0; m < 4; ++m)
      #pragma unroll
      for (int n = 0; n < 4; ++n)
        acc[m][n] = __builtin_amdgcn_mfma_f32_16x16x32_bf16(a0[m], bf[n], acc[m][n], 0, 0, 0);
    __builtin_amdgcn_s_setprio(0);

    // ---- phase 1: issue B-stage(kt+2) ; A m4-7 ; 16 MFMA ----
    if (pf) {
      gload_lds16(gb,       Ln + 8192 + sdst);
      gload_lds16(gb + p1a, Ln + 12288 + sdst);
    }
    short8 a1[4];
    #pragma unroll
    for (int m = 0; m < 4; ++m) a1[m] = *(const short8*)(Lb + aBase + (m + 4) * 512);
    __builtin_amdgcn_s_setprio(1);
    #pragma unroll
    for (int m = 0; m < 4; ++m)
      #pragma unroll
      for (int n = 0; n < 4; ++n)
        acc[m + 4][n] = __builtin_amdgcn_mfma_f32_16x16x32_bf16(a1[m], bf[n], acc[m + 4][n], 0, 0, 0);
    __builtin_amdgcn_s_setprio(0);

    // counted drain: kt+1's 4 loads complete; kt+2's 4 stay in flight
    if (pf) asm volatile("s_waitcnt vmcnt(4)" ::: "memory");
    else    asm volatile("s_waitcnt vmcnt(0)" ::: "memory");
    __builtin_amdgcn_s_barrier();
    asm volatile("" ::: "memory");
  }

  // ---- epilogue ----
  const int col0 = bn + wc * 64 + l15;
  if (EPI <= 1) {
    float bvv[4];
    #pragma unroll
    for (int n = 0; n < 4; ++n) bvv[n] = bias[col0 + n * 16];
    #pragma unroll
    for (int m = 0; m < 8; ++m) {
      #pragma unroll
      for (int ri = 0; ri < 4; ++ri) {
        const size_t row = (size_t)(bm + wr * 128 + m * 16 + l4 * 4 + ri);
        u16* cp = C + row * N + col0;
        #pragma unroll
        for (int n = 0; n < 4; ++n) {
          float vv = acc[m][n][ri] + bvv[n];
          if (EPI == 1) vv = 0.5f * vv * (1.0f + erff(vv * 0.70710678118654752f));
          cp[n * 16] = f2b(vv);
        }
      }
    }
  } else {
    u16* o = (bz == 0) ? C : C2;
    #pragma unroll
    for (int m = 0; m < 8; ++m) {
      #pragma unroll
      for (int ri = 0; ri < 4; ++ri) {
        const size_t row = (size_t)(bm + wr * 128 + m * 16 + l4 * 4 + ri);
        u16* cp = o + row * N + col0;
        #pragma unroll
        for (int n = 0; n < 4; ++n) cp[n * 16] = f2b(acc[m][n][ri]);
      }
    }
  }
}

// ---------------------------------------------------------------------------
// Banded-Gram attention. One block per (b, 32-pos chunk, head).
// ---------------------------------------------------------------------------
#define ATL 32
#define ART (ATL + 8)   // 40 staged rows

__global__ __launch_bounds__(256) void attn_band(
    const u16* __restrict__ QKV, const float* __restrict__ bqkv,
    const float* __restrict__ bo, u16* __restrict__ newx) {
  __shared__ __align__(16) u16 S3[3][ART][72];
  __shared__ float Gb[ART][18];
  __shared__ float Sm[ART][81];
  __shared__ float Wb[ATL][9];

  const int tid = threadIdx.x;
  const int bid = ((int)blockIdx.x & 7) * 256 + ((int)blockIdx.x >> 3);
  const int h = bid & 7;
  const int chunk = (bid >> 3) & 63;
  const int b = bid >> 9;
  const int l0 = chunk * ATL;

  for (int idx = tid; idx < ART * 24; idx += 256) {
    const int ti = idx / 24, c = idx % 24;
    const int slice = c >> 3, d8 = (c & 7) * 8;
    const int col = slice * 512 + h * 64 + d8;
    const int t = l0 - 4 + ti;
    short8 v;
    if ((unsigned)t < 2048u) {
      v = *(const short8*)(QKV + ((size_t)((b << 11) | t)) * 1536 + col);
    } else {
      #pragma unroll
      for (int j = 0; j < 8; ++j) v[j] = (short)f2b(bqkv[col + j]);
    }
    *(short8*)(&S3[slice][ti][d8]) = v;
  }
  __syncthreads();

  for (int task = tid; task < ART * 17; task += 256) {
    const int ti = task / 17, j = task % 17;
    const int ui = ti + j - 8;
    if ((unsigned)ui < (unsigned)ART) {
      float a = 0.f;
      #pragma unroll
      for (int d0 = 0; d0 < 64; d0 += 8) {
        short8 qv = *(const short8*)(&S3[0][ti][d0]);
        short8 kv = *(const short8*)(&S3[1][ui][d0]);
        #pragma unroll
        for (int jj = 0; jj < 8; ++jj) a += b2f((u16)qv[jj]) * b2f((u16)kv[jj]);
      }
      Gb[ti][j] = a * 0.125f;
    }
  }
  __syncthreads();

  for (int task = tid; task < ART * 9; task += 256) {
    const int ti = task / 9, qw = task % 9;
    const int li = ti - qw;
    if ((unsigned)li < (unsigned)ATL) {
      float m = -1e30f;
      #pragma unroll
      for (int kw = 0; kw < 9; ++kw) m = fmaxf(m, Gb[ti][kw - qw + 8]);
      float e[9], s = 0.f;
      #pragma unroll
      for (int kw = 0; kw < 9; ++kw) { e[kw] = expf(Gb[ti][kw - qw + 8] - m); s += e[kw]; }
      const float inv = 1.f / s;
      #pragma unroll
      for (int kw = 0; kw < 9; ++kw) Sm[ti][qw * 9 + kw] = e[kw] * inv;
    }
  }
  __syncthreads();

  for (int task = tid; task < ATL * 9; task += 256) {
    const int li = task / 9, kw = task % 9;
    float s = 0.f;
    #pragma unroll
    for (int qw = 0; qw < 9; ++qw) s += Sm[li + qw][qw * 9 + kw];
    Wb[li][kw] = s * (1.f / 9.f);
  }
  __syncthreads();

  {
    const int li = tid >> 3, d8 = (tid & 7) * 8;
    float w[9];
    #pragma unroll
    for (int kw = 0; kw < 9; ++kw) w[kw] = Wb[li][kw];
    float a[8] = {};
    #pragma unroll
    for (int kw = 0; kw < 9; ++kw) {
      short8 vv = *(const short8*)(&S3[2][li + kw][d8]);
      #pragma unroll
      for (int jj = 0; jj < 8; ++jj) a[jj] += w[kw] * b2f((u16)vv[jj]);
    }
    short8 o;
    #pragma unroll
    for (int jj = 0; jj < 8; ++jj) o[jj] = (short)f2b(a[jj] + bo[h * 64 + d8 + jj]);
    const int l = l0 + li;
    *(short8*)(newx + ((size_t)((b << 11) | l)) * 512 + h * 64 + d8) = o;
  }
}

// ---------------------------------------------------------------------------
// LayerNorm over D=512. One wave per row, 4 rows/block.
// MODE 0: v = a + b                  -> bf16 out
// MODE 1: v = a + b + c + bias[col]  -> fp32 out
// ---------------------------------------------------------------------------
template<int MODE>
__global__ __launch_bounds__(256) void ln_kernel(
    const u16* __restrict__ a, const u16* __restrict__ bsrc,
    const u16* __restrict__ csrc, const float* __restrict__ bias,
    const float* __restrict__ g, const float* __restrict__ be,
    u16* __restrict__ outb, float* __restrict__ outf) {
  const int wave = threadIdx.x >> 6, lane = threadIdx.x & 63;
  const size_t row = (size_t)blockIdx.x * 4 + wave;
  const size_t base = row * 512 + lane * 8;
  const int gi = lane * 8;
  float v[8];
  short8 a8 = *(const short8*)(a + base);
  short8 b8 = *(const short8*)(bsrc + base);
  #pragma unroll
  for (int j = 0; j < 8; ++j) v[j] = b2f((u16)a8[j]) + b2f((u16)b8[j]);
  if (MODE == 1) {
    short8 c8 = *(const short8*)(csrc + base);
    #pragma unroll
    for (int j = 0; j < 8; ++j) v[j] += b2f((u16)c8[j]) + bias[gi + j];
  }

  float s = 0.f;
  #pragma unroll
  for (int j = 0; j < 8; ++j) s += v[j];
  #pragma unroll
  for (int off = 32; off >= 1; off >>= 1) s += __shfl_xor(s, off, 64);
  const float mean = s * (1.f / 512.f);
  float sq = 0.f;
  #pragma unroll
  for (int j = 0; j < 8; ++j) { float d = v[j] - mean; sq += d * d; }
  #pragma unroll
  for (int off = 32; off >= 1; off >>= 1) sq += __shfl_xor(sq, off, 64);
  const float rs = rsqrtf(sq * (1.f / 512.f) + 1e-5f);

  if (MODE == 0) {
    short8 o;
    #pragma unroll
    for (int j = 0; j < 8; ++j)
      o[j] = (short)f2b((v[j] - mean) * rs * g[gi + j] + be[gi + j]);
    *(short8*)(outb + base) = o;
  } else {
    float4 o0, o1;
    o0.x = (v[0] - mean) * rs * g[gi + 0] + be[gi + 0];
    o0.y = (v[1] - mean) * rs * g[gi + 1] + be[gi + 1];
    o0.z = (v[2] - mean) * rs * g[gi + 2] + be[gi + 2];
    o0.w = (v[3] - mean) * rs * g[gi + 3] + be[gi + 3];
    o1.x = (v[4] - mean) * rs * g[gi + 4] + be[gi + 4];
    o1.y = (v[5] - mean) * rs * g[gi + 5] + be[gi + 5];
    o1.z = (v[6] - mean) * rs * g[gi + 6] + be[gi + 6];
    o1.w = (v[7] - mean) * rs * g[gi + 7] + be[gi + 7];
    *(float4*)(outf + base) = o0;
    *(float4*)(outf + base + 4) = o1;
  }
}

// ---------------------------------------------------------------------------
extern "C" void kernel_launch(void* const* d_in, const int* in_sizes, int n_in,
                              void* d_out, int out_size, void* d_ws, size_t ws_size,
                              hipStream_t stream) {
  const float* x   = (const float*)d_in[0];
  const float* Wq  = (const float*)d_in[1];
  const float* bq  = (const float*)d_in[2];
  const float* Wk  = (const float*)d_in[3];
  const float* bk  = (const float*)d_in[4];
  const float* Wv  = (const float*)d_in[5];
  const float* bv  = (const float*)d_in[6];
  const float* Wo  = (const float*)d_in[7];
  const float* bo  = (const float*)d_in[8];
  const float* W1  = (const float*)d_in[9];
  const float* b1  = (const float*)d_in[10];
  const float* W2  = (const float*)d_in[11];
  const float* b2  = (const float*)d_in[12];
  const float* g1  = (const float*)d_in[13];
  const float* be1 = (const float*)d_in[14];
  const float* g2  = (const float*)d_in[15];
  const float* be2 = (const float*)d_in[16];

  char* w = (char*)d_ws;
  u16*   xb    = (u16*)  (w + 0);           // 8 MB; reused as y-partial-1 after LN1
  u16*   WqkvT = (u16*)  (w + 8388608);     // [1536][512] bf16 (q,k,vo)
  u16*   WoT   = (u16*)  (w + 9961472);     // legacy
  u16*   W1T   = (u16*)  (w + 10485760);    // [2048][512]
  u16*   W2T   = (u16*)  (w + 12582912);    // [512][2048]
  float* bqkv  = (float*)(w + 14680064);    // 2048 f32 (bq,bk,bvo,zeros)
  u16*   Wvb   = (u16*)  (w + 14688256);    // legacy
  u16*   QKV   = (u16*)  (w + 15212544);    // 8192x1536 bf16 (dead after attn)
  u16*   hbuf  = QKV;                       // 8192x2048 bf16 (aliases QKV)
  u16*   newx  = (u16*)  (w + 48766976);    // 8192x512 bf16; y-partial-0 after LN1
  u16*   x1b   = (u16*)  (w + 57155584);    // 8192x512 bf16
  u16*   WvoT  = WqkvT + 524288;            // V region of WqkvT = (Wv@Wo)^T
  u16*   yp0   = newx;                      // G4 split-K partial z=0
  u16*   yp1   = xb;                        // G4 split-K partial z=1

  // --- prep ---
  prep_weights<<<3072, 256, 0, stream>>>(Wq, Wk, Wo, W1, W2, Wv,
                                         WqkvT, WoT, W1T, W2T, Wvb);
  bias_prep<<<8, 256, 0, stream>>>(bq, bk, bqkv);
  wvo_kernel<<<dim3(8, 8), 256, 0, stream>>>(Wv, Wo, bv, WvoT, bqkv + 1024);
  f2b_vec<<<4096, 256, 0, stream>>>(x, xb, 1048576);
  // --- G1: QKV'' ---
  gemm_big<0><<<dim3(6, 32, 1), 512, 0, stream>>>(xb, WqkvT, bqkv, QKV, nullptr,
                                                  8192, 1536, 512, 512);
  // --- attention (banded Gram) -> newx ---
  attn_band<<<2048, 256, 0, stream>>>(QKV, bqkv, bo, newx);
  // --- LN1: x1 = LN(xb + newx) ---
  ln_kernel<0><<<2048, 256, 0, stream>>>(xb, newx, nullptr, nullptr, g1, be1, x1b, nullptr);
  // --- G3: h = gelu(x1 @ W1T^T + b1) ---
  gemm_big<1><<<dim3(8, 32, 1), 512, 0, stream>>>(x1b, W1T, b1, hbuf, nullptr,
                                                  8192, 2048, 512, 512);
  // --- G4: y partials (split-K=2) ---
  gemm_big<2><<<dim3(2, 32, 2), 512, 0, stream>>>(hbuf, W2T, nullptr, yp0, yp1,
                                                  8192, 512, 2048, 1024);
  // --- LN2 -> out ---
  ln_kernel<1><<<2048, 256, 0, stream>>>(x1b, yp0, yp1, b2, g2, be2, nullptr, (float*)d_out);
}

// Round 7
// 181.435 us; speedup vs baseline: 1.5718x; 1.1325x over previous
//
#include <hip/hip_runtime.h>

// ---------------------------------------------------------------------------
// LocalWindowAttentionLayer on MI355X (gfx950)
// B=4 L=2048 D=512 H=8 DK=64 DF=2048 W=9
//
// Pipeline (G2 folded into G1 via Wvo = Wv@Wo):
//  prep: transpose Wq,Wk,W1,W2 -> bf16 [N][K]; bias prep; Wvo fp32 tile GEMM
//  G1 : QKV'' = xb @ [Wq;Wk;Wvo]^T + [bq;bk;bvo]   (8192 x 1536, K=512)
//  A  : banded-Gram attention -> newx (8192 x 512)
//  LN1: x1 = LN(xb + newx)
//  G3 : h = gelu(x1 @ W1T^T + b1)       (8192 x 2048, K=512)
//  G4 : y = h @ W2T^T  (split-K=2 -> 2 bf16 partials)
//  LN2: out = LN(x1 + y0 + y1 + b2) -> fp32
//
// gemm (R7): OCCUPANCY-FIRST. Empirical law from R2-R6: dur*occ ~= const
// (latency-bound). Tile 128x64, 4 waves (2Mx2N, wave 64x32, acc[4][2]),
// BK=32, 2-buf LDS = 24KB, ~92 regs -> 5 waves/SIMD (62.5% occ) vs 40% before.
// Granule-permuted LDS (conflict-free, R4-verified), XCD-chunked swizzle.
// No setprio (m190: negative on lockstep GEMM).
// ---------------------------------------------------------------------------

typedef unsigned short u16;
typedef __attribute__((ext_vector_type(8))) short short8;   // 8 bf16
typedef __attribute__((ext_vector_type(4))) float floatx4;  // MFMA acc

#define DEV static __device__ __forceinline__

DEV float b2f(u16 u) {
  union { unsigned int i; float f; } x; x.i = ((unsigned int)u) << 16; return x.f;
}
DEV u16 f2b(float f) {  // round-to-nearest-even
  union { float f; unsigned int i; } x; x.f = f;
  unsigned int u = x.i + 0x7fffu + ((x.i >> 16) & 1u);
  return (u16)(u >> 16);
}

#define AS1 __attribute__((address_space(1)))
#define AS3 __attribute__((address_space(3)))
DEV void gload_lds16(const void* g, void* l) {
  __builtin_amdgcn_global_load_lds((const AS1 void*)g, (AS3 void*)l, 16, 0, 0);
}

// ---------------------------------------------------------------------------
// Weight prep: transposes (fp32 RxC -> bf16 CxR) for Wq,Wk,W1,W2.
// blocks: [0,256) Wq | [256,512) Wk | [512,1536) W1 | [1536,2560) W2
// ---------------------------------------------------------------------------
__global__ __launch_bounds__(256) void prep_weights(
    const float* __restrict__ Wq, const float* __restrict__ Wk,
    const float* __restrict__ W1, const float* __restrict__ W2,
    u16* __restrict__ WqkvT, u16* __restrict__ W1T, u16* __restrict__ W2T) {
  const int bid = blockIdx.x;
  const float* in; u16* out; int R, C, t;
  if (bid < 256)       { in = Wq; out = WqkvT;          R = 512;  C = 512;  t = bid; }
  else if (bid < 512)  { in = Wk; out = WqkvT + 262144; R = 512;  C = 512;  t = bid - 256; }
  else if (bid < 1536) { in = W1; out = W1T;            R = 512;  C = 2048; t = bid - 512; }
  else                 { in = W2; out = W2T;            R = 2048; C = 512;  t = bid - 1536; }
  const int tpr = C >> 5;
  const int bc = (t % tpr) * 32, br = (t / tpr) * 32;
  __shared__ float tile[32][33];
  const int tx = threadIdx.x & 31, ty = threadIdx.x >> 5;
  #pragma unroll
  for (int i = 0; i < 32; i += 8)
    tile[ty + i][tx] = in[(size_t)(br + ty + i) * C + bc + tx];
  __syncthreads();
  #pragma unroll
  for (int i = 0; i < 32; i += 8)
    out[(size_t)(bc + ty + i) * R + br + tx] = f2b(tile[tx][ty + i]);
}

// bqkv[0:512)=bq, [512:1024)=bk, [1536:2048)=0.  ([1024:1536)=bvo from wvo_kernel)
__global__ __launch_bounds__(256) void bias_prep(
    const float* __restrict__ bq, const float* __restrict__ bk,
    float* __restrict__ o) {
  const int i = blockIdx.x * 256 + threadIdx.x;
  if (i < 512) o[i] = bq[i];
  else if (i < 1024) o[i] = bk[i - 512];
  else if (i >= 1536 && i < 2048) o[i] = 0.f;
}

// ---------------------------------------------------------------------------
// Wvo = Wv@Wo (fp32 in, bf16 out, transposed): WvoT[n][k] = sum_j Wv[k][j]Wo[j][n]
// Also bvo[n] = sum_j bv[j]*Wo[j][n] (blocks with tk==0).
// ---------------------------------------------------------------------------
__global__ __launch_bounds__(256) void wvo_kernel(
    const float* __restrict__ Wv, const float* __restrict__ Wo,
    const float* __restrict__ bv,
    u16* __restrict__ WvoT, float* __restrict__ bvo) {
  __shared__ float Vs[64][65];
  __shared__ float Os[64][65];
  const int tn = blockIdx.x, tk = blockIdx.y;
  const int tid = threadIdx.x;
  const int tx = tid & 15, ty = tid >> 4;
  const int k0 = tk * 64, n0 = tn * 64;
  float acc[4][4] = {};
  float bacc = 0.f;
  for (int j0 = 0; j0 < 512; j0 += 64) {
    for (int i = tid; i < 64 * 64; i += 256) {
      const int r = i >> 6, c = i & 63;
      Vs[r][c] = Wv[(size_t)(k0 + r) * 512 + j0 + c];
      Os[r][c] = Wo[(size_t)(j0 + r) * 512 + n0 + c];
    }
    __syncthreads();
    #pragma unroll 4
    for (int j = 0; j < 64; ++j) {
      float vv[4], ov[4];
      #pragma unroll
      for (int a = 0; a < 4; ++a) vv[a] = Vs[ty * 4 + a][j];
      #pragma unroll
      for (int b = 0; b < 4; ++b) ov[b] = Os[j][tx * 4 + b];
      #pragma unroll
      for (int a = 0; a < 4; ++a)
        #pragma unroll
        for (int b = 0; b < 4; ++b) acc[a][b] += vv[a] * ov[b];
    }
    if (tk == 0 && tid < 64) {
      float s = 0.f;
      for (int jj = 0; jj < 64; ++jj) s += bv[j0 + jj] * Os[jj][tid];
      bacc += s;
    }
    __syncthreads();
  }
  #pragma unroll
  for (int a = 0; a < 4; ++a)
    #pragma unroll
    for (int b = 0; b < 4; ++b)
      WvoT[(size_t)(n0 + tx * 4 + b) * 512 + k0 + ty * 4 + a] = f2b(acc[a][b]);
  if (tk == 0 && tid < 64) bvo[n0 + tid] = bacc;
}

__global__ __launch_bounds__(256) void f2b_vec(
    const float* __restrict__ in, u16* __restrict__ out, int n4) {
  int i = blockIdx.x * 256 + threadIdx.x;
  if (i < n4) {
    float4 v = ((const float4*)in)[i];
    ushort4 o;
    o.x = f2b(v.x); o.y = f2b(v.y); o.z = f2b(v.z); o.w = f2b(v.w);
    ((ushort4*)out)[i] = o;
  }
}

// ---------------------------------------------------------------------------
// High-occupancy bf16 MFMA GEMM.  C = A[M][lda] @ BT[N][lda]^T (+ bias)
// EPI: 0=bias->bf16, 1=bias+gelu->bf16, 2=raw bf16 partial (split-K via z)
// BM=128, BN=64, BK=32; 256 thr = 4 waves (wr=w&1 M-half, wc=w>>1 N-half),
// wave tile 64x32 -> acc[4][2].  LDS 2 x (A 8KB | B 4KB) = 24KB.
// Granule permute: physical slot g at row r holds logical g-(r>>1) (mod 4);
// applied on the global SOURCE granule (linear global_load_lds dest, rule #21)
// and on the fragment-read slot -> conflict-free (R4-verified).
// ---------------------------------------------------------------------------
template<int EPI>
__global__ __launch_bounds__(256, 5) void gemm_bt(
    const u16* __restrict__ A, const u16* __restrict__ BT,
    const float* __restrict__ bias, u16* __restrict__ C, u16* __restrict__ C2,
    int M, int N, int lda, int kb) {
  __shared__ __align__(16) u16 As[2][4096];
  __shared__ __align__(16) u16 Bs[2][2048];
  const int tid = threadIdx.x;
  const int w = tid >> 6, l = tid & 63;
  const int l15 = l & 15, l4 = l >> 4;
  const int wr = w & 1, wc = w >> 1;

  // T1: XCD-chunked swizzle (guard nwg%8)
  const int gx = (int)gridDim.x, gy = (int)gridDim.y;
  int id = ((int)blockIdx.z * gy + (int)blockIdx.y) * gx + (int)blockIdx.x;
  const int nwg = gx * gy * (int)gridDim.z;
  if ((nwg & 7) == 0) { const int cpx = nwg >> 3; id = (id & 7) * cpx + (id >> 3); }
  const int bx = id % gx; const int r1 = id / gx;
  const int by = r1 % gy; const int bz = r1 / gy;
  const int bm = by * 128, bn = bx * 64;
  const int koff = bz * kb;

  // staging: thread -> (row0 = tid>>2, permuted source granule)
  const int row0 = tid >> 2;
  const int kc0 = ((((tid & 3) - ((tid >> 3) & 3)) & 3)) * 8;
  const u16* gA = A  + (size_t)(bm + row0) * lda + koff + kc0;
  const u16* gB = BT + (size_t)(bn + row0) * lda + koff + kc0;
  const size_t a1 = (size_t)64 * lda;      // A pass-1 row offset
  const int sd = w * 512 + l * 8;          // linear, wave-contiguous LDS dest

  // fragment read offsets: slot = (l4 + (row>>1)) & 3; (row>>1)&3 == (l15>>1)&3
  const int rg8 = ((l4 + ((l15 >> 1) & 3)) & 3) * 8;
  const int aBase = (wr * 64 + l15) * 32 + rg8;
  const int bBase = (wc * 32 + l15) * 32 + rg8;

  floatx4 acc[4][2] = {};
  const int nt = kb >> 5;

  gload_lds16(gA,      &As[0][sd]);
  gload_lds16(gA + a1, &As[0][2048 + sd]);
  gload_lds16(gB,      &Bs[0][sd]);
  asm volatile("s_waitcnt vmcnt(0)" ::: "memory");
  __builtin_amdgcn_s_barrier();
  asm volatile("" ::: "memory");

  for (int t = 0; t < nt; ++t) {
    const int cur = t & 1;
    if (t + 1 < nt) {
      const u16* a = gA + (size_t)(t + 1) * 32;
      const u16* b = gB + (size_t)(t + 1) * 32;
      gload_lds16(a,      &As[cur ^ 1][sd]);
      gload_lds16(a + a1, &As[cur ^ 1][2048 + sd]);
      gload_lds16(b,      &Bs[cur ^ 1][sd]);
    }
    short8 af[4], bf[2];
    #pragma unroll
    for (int m = 0; m < 4; ++m) af[m] = *(const short8*)(&As[cur][aBase + m * 512]);
    #pragma unroll
    for (int n = 0; n < 2; ++n) bf[n] = *(const short8*)(&Bs[cur][bBase + n * 512]);
    #pragma unroll
    for (int m = 0; m < 4; ++m)
      #pragma unroll
      for (int n = 0; n < 2; ++n)
        acc[m][n] = __builtin_amdgcn_mfma_f32_16x16x32_bf16(af[m], bf[n], acc[m][n], 0, 0, 0);
    asm volatile("s_waitcnt vmcnt(0)" ::: "memory");
    __builtin_amdgcn_s_barrier();
    asm volatile("" ::: "memory");
  }

  // ---- epilogue ----
  const int col0 = bn + wc * 32 + l15;
  if (EPI <= 1) {
    float bvv[2];
    #pragma unroll
    for (int n = 0; n < 2; ++n) bvv[n] = bias[col0 + n * 16];
    #pragma unroll
    for (int m = 0; m < 4; ++m) {
      #pragma unroll
      for (int ri = 0; ri < 4; ++ri) {
        const size_t row = (size_t)(bm + wr * 64 + m * 16 + l4 * 4 + ri);
        u16* cp = C + row * N + col0;
        #pragma unroll
        for (int n = 0; n < 2; ++n) {
          float vv = acc[m][n][ri] + bvv[n];
          if (EPI == 1) vv = 0.5f * vv * (1.0f + erff(vv * 0.70710678118654752f));
          cp[n * 16] = f2b(vv);
        }
      }
    }
  } else {
    u16* o = (bz == 0) ? C : C2;
    #pragma unroll
    for (int m = 0; m < 4; ++m) {
      #pragma unroll
      for (int ri = 0; ri < 4; ++ri) {
        const size_t row = (size_t)(bm + wr * 64 + m * 16 + l4 * 4 + ri);
        u16* cp = o + row * N + col0;
        #pragma unroll
        for (int n = 0; n < 2; ++n) cp[n * 16] = f2b(acc[m][n][ri]);
      }
    }
  }
}

// ---------------------------------------------------------------------------
// Banded-Gram attention. One block per (b, 32-pos chunk, head).
// ---------------------------------------------------------------------------
#define ATL 32
#define ART (ATL + 8)   // 40 staged rows

__global__ __launch_bounds__(256) void attn_band(
    const u16* __restrict__ QKV, const float* __restrict__ bqkv,
    const float* __restrict__ bo, u16* __restrict__ newx) {
  __shared__ __align__(16) u16 S3[3][ART][72];
  __shared__ float Gb[ART][18];
  __shared__ float Sm[ART][81];
  __shared__ float Wb[ATL][9];

  const int tid = threadIdx.x;
  const int bid = ((int)blockIdx.x & 7) * 256 + ((int)blockIdx.x >> 3);
  const int h = bid & 7;
  const int chunk = (bid >> 3) & 63;
  const int b = bid >> 9;
  const int l0 = chunk * ATL;

  for (int idx = tid; idx < ART * 24; idx += 256) {
    const int ti = idx / 24, c = idx % 24;
    const int slice = c >> 3, d8 = (c & 7) * 8;
    const int col = slice * 512 + h * 64 + d8;
    const int t = l0 - 4 + ti;
    short8 v;
    if ((unsigned)t < 2048u) {
      v = *(const short8*)(QKV + ((size_t)((b << 11) | t)) * 1536 + col);
    } else {
      #pragma unroll
      for (int j = 0; j < 8; ++j) v[j] = (short)f2b(bqkv[col + j]);
    }
    *(short8*)(&S3[slice][ti][d8]) = v;
  }
  __syncthreads();

  for (int task = tid; task < ART * 17; task += 256) {
    const int ti = task / 17, j = task % 17;
    const int ui = ti + j - 8;
    if ((unsigned)ui < (unsigned)ART) {
      float a = 0.f;
      #pragma unroll
      for (int d0 = 0; d0 < 64; d0 += 8) {
        short8 qv = *(const short8*)(&S3[0][ti][d0]);
        short8 kv = *(const short8*)(&S3[1][ui][d0]);
        #pragma unroll
        for (int jj = 0; jj < 8; ++jj) a += b2f((u16)qv[jj]) * b2f((u16)kv[jj]);
      }
      Gb[ti][j] = a * 0.125f;
    }
  }
  __syncthreads();

  for (int task = tid; task < ART * 9; task += 256) {
    const int ti = task / 9, qw = task % 9;
    const int li = ti - qw;
    if ((unsigned)li < (unsigned)ATL) {
      float m = -1e30f;
      #pragma unroll
      for (int kw = 0; kw < 9; ++kw) m = fmaxf(m, Gb[ti][kw - qw + 8]);
      float e[9], s = 0.f;
      #pragma unroll
      for (int kw = 0; kw < 9; ++kw) { e[kw] = expf(Gb[ti][kw - qw + 8] - m); s += e[kw]; }
      const float inv = 1.f / s;
      #pragma unroll
      for (int kw = 0; kw < 9; ++kw) Sm[ti][qw * 9 + kw] = e[kw] * inv;
    }
  }
  __syncthreads();

  for (int task = tid; task < ATL * 9; task += 256) {
    const int li = task / 9, kw = task % 9;
    float s = 0.f;
    #pragma unroll
    for (int qw = 0; qw < 9; ++qw) s += Sm[li + qw][qw * 9 + kw];
    Wb[li][kw] = s * (1.f / 9.f);
  }
  __syncthreads();

  {
    const int li = tid >> 3, d8 = (tid & 7) * 8;
    float w[9];
    #pragma unroll
    for (int kw = 0; kw < 9; ++kw) w[kw] = Wb[li][kw];
    float a[8] = {};
    #pragma unroll
    for (int kw = 0; kw < 9; ++kw) {
      short8 vv = *(const short8*)(&S3[2][li + kw][d8]);
      #pragma unroll
      for (int jj = 0; jj < 8; ++jj) a[jj] += w[kw] * b2f((u16)vv[jj]);
    }
    short8 o;
    #pragma unroll
    for (int jj = 0; jj < 8; ++jj) o[jj] = (short)f2b(a[jj] + bo[h * 64 + d8 + jj]);
    const int l = l0 + li;
    *(short8*)(newx + ((size_t)((b << 11) | l)) * 512 + h * 64 + d8) = o;
  }
}

// ---------------------------------------------------------------------------
// LayerNorm over D=512. One wave per row, 4 rows/block.
// MODE 0: v = a + b                  -> bf16 out
// MODE 1: v = a + b + c + bias[col]  -> fp32 out
// ---------------------------------------------------------------------------
template<int MODE>
__global__ __launch_bounds__(256) void ln_kernel(
    const u16* __restrict__ a, const u16* __restrict__ bsrc,
    const u16* __restrict__ csrc, const float* __restrict__ bias,
    const float* __restrict__ g, const float* __restrict__ be,
    u16* __restrict__ outb, float* __restrict__ outf) {
  const int wave = threadIdx.x >> 6, lane = threadIdx.x & 63;
  const size_t row = (size_t)blockIdx.x * 4 + wave;
  const size_t base = row * 512 + lane * 8;
  const int gi = lane * 8;
  float v[8];
  short8 a8 = *(const short8*)(a + base);
  short8 b8 = *(const short8*)(bsrc + base);
  #pragma unroll
  for (int j = 0; j < 8; ++j) v[j] = b2f((u16)a8[j]) + b2f((u16)b8[j]);
  if (MODE == 1) {
    short8 c8 = *(const short8*)(csrc + base);
    #pragma unroll
    for (int j = 0; j < 8; ++j) v[j] += b2f((u16)c8[j]) + bias[gi + j];
  }

  float s = 0.f;
  #pragma unroll
  for (int j = 0; j < 8; ++j) s += v[j];
  #pragma unroll
  for (int off = 32; off >= 1; off >>= 1) s += __shfl_xor(s, off, 64);
  const float mean = s * (1.f / 512.f);
  float sq = 0.f;
  #pragma unroll
  for (int j = 0; j < 8; ++j) { float d = v[j] - mean; sq += d * d; }
  #pragma unroll
  for (int off = 32; off >= 1; off >>= 1) sq += __shfl_xor(sq, off, 64);
  const float rs = rsqrtf(sq * (1.f / 512.f) + 1e-5f);

  if (MODE == 0) {
    short8 o;
    #pragma unroll
    for (int j = 0; j < 8; ++j)
      o[j] = (short)f2b((v[j] - mean) * rs * g[gi + j] + be[gi + j]);
    *(short8*)(outb + base) = o;
  } else {
    float4 o0, o1;
    o0.x = (v[0] - mean) * rs * g[gi + 0] + be[gi + 0];
    o0.y = (v[1] - mean) * rs * g[gi + 1] + be[gi + 1];
    o0.z = (v[2] - mean) * rs * g[gi + 2] + be[gi + 2];
    o0.w = (v[3] - mean) * rs * g[gi + 3] + be[gi + 3];
    o1.x = (v[4] - mean) * rs * g[gi + 4] + be[gi + 4];
    o1.y = (v[5] - mean) * rs * g[gi + 5] + be[gi + 5];
    o1.z = (v[6] - mean) * rs * g[gi + 6] + be[gi + 6];
    o1.w = (v[7] - mean) * rs * g[gi + 7] + be[gi + 7];
    *(float4*)(outf + base) = o0;
    *(float4*)(outf + base + 4) = o1;
  }
}

// ---------------------------------------------------------------------------
extern "C" void kernel_launch(void* const* d_in, const int* in_sizes, int n_in,
                              void* d_out, int out_size, void* d_ws, size_t ws_size,
                              hipStream_t stream) {
  const float* x   = (const float*)d_in[0];
  const float* Wq  = (const float*)d_in[1];
  const float* bq  = (const float*)d_in[2];
  const float* Wk  = (const float*)d_in[3];
  const float* bk  = (const float*)d_in[4];
  const float* Wv  = (const float*)d_in[5];
  const float* bv  = (const float*)d_in[6];
  const float* Wo  = (const float*)d_in[7];
  const float* bo  = (const float*)d_in[8];
  const float* W1  = (const float*)d_in[9];
  const float* b1  = (const float*)d_in[10];
  const float* W2  = (const float*)d_in[11];
  const float* b2  = (const float*)d_in[12];
  const float* g1  = (const float*)d_in[13];
  const float* be1 = (const float*)d_in[14];
  const float* g2  = (const float*)d_in[15];
  const float* be2 = (const float*)d_in[16];

  char* w = (char*)d_ws;
  u16*   xb    = (u16*)  (w + 0);           // 8 MB; reused as y-partial-1 after LN1
  u16*   WqkvT = (u16*)  (w + 8388608);     // [1536][512] bf16 (q,k,vo)
  u16*   W1T   = (u16*)  (w + 10485760);    // [2048][512]
  u16*   W2T   = (u16*)  (w + 12582912);    // [512][2048]
  float* bqkv  = (float*)(w + 14680064);    // 2048 f32 (bq,bk,bvo,zeros)
  u16*   QKV   = (u16*)  (w + 15212544);    // 8192x1536 bf16 (dead after attn)
  u16*   hbuf  = QKV;                       // 8192x2048 bf16 (aliases QKV)
  u16*   newx  = (u16*)  (w + 48766976);    // 8192x512 bf16; y-partial-0 after LN1
  u16*   x1b   = (u16*)  (w + 57155584);    // 8192x512 bf16
  u16*   WvoT  = WqkvT + 524288;            // V region of WqkvT = (Wv@Wo)^T
  u16*   yp0   = newx;                      // G4 split-K partial z=0
  u16*   yp1   = xb;                        // G4 split-K partial z=1

  // --- prep ---
  prep_weights<<<2560, 256, 0, stream>>>(Wq, Wk, W1, W2, WqkvT, W1T, W2T);
  bias_prep<<<8, 256, 0, stream>>>(bq, bk, bqkv);
  wvo_kernel<<<dim3(8, 8), 256, 0, stream>>>(Wv, Wo, bv, WvoT, bqkv + 1024);
  f2b_vec<<<4096, 256, 0, stream>>>(x, xb, 1048576);
  // --- G1: QKV'' ---
  gemm_bt<0><<<dim3(24, 64, 1), 256, 0, stream>>>(xb, WqkvT, bqkv, QKV, nullptr,
                                                  8192, 1536, 512, 512);
  // --- attention (banded Gram) -> newx ---
  attn_band<<<2048, 256, 0, stream>>>(QKV, bqkv, bo, newx);
  // --- LN1: x1 = LN(xb + newx) ---
  ln_kernel<0><<<2048, 256, 0, stream>>>(xb, newx, nullptr, nullptr, g1, be1, x1b, nullptr);
  // --- G3: h = gelu(x1 @ W1T^T + b1) ---
  gemm_bt<1><<<dim3(32, 64, 1), 256, 0, stream>>>(x1b, W1T, b1, hbuf, nullptr,
                                                  8192, 2048, 512, 512);
  // --- G4: y partials (split-K=2) ---
  gemm_bt<2><<<dim3(8, 64, 2), 256, 0, stream>>>(hbuf, W2T, nullptr, yp0, yp1,
                                                 8192, 512, 2048, 1024);
  // --- LN2 -> out ---
  ln_kernel<1><<<2048, 256, 0, stream>>>(x1b, yp0, yp1, b2, g2, be2, nullptr, (float*)d_out);
}

// Round 8
// 164.089 us; speedup vs baseline: 1.7379x; 1.1057x over previous
//
#include <hip/hip_runtime.h>

// ---------------------------------------------------------------------------
// LocalWindowAttentionLayer on MI355X (gfx950)
// B=4 L=2048 D=512 H=8 DK=64 DF=2048 W=9
//
// Pipeline (G2 folded into G1 via Wvo = Wv@Wo):
//  prep: transpose Wq,Wk,Wo,W1,W2 -> bf16 [N][K]; Wv -> bf16; bias prep
//  Wvo: WvoT = gemm(WoT, Wvb) via MFMA GEMM (32 blocks, ~3us; replaces the
//       54us/2%-occupancy scalar wvo_kernel found in R7 profiling)
//  G1 : QKV'' = xb @ [Wq;Wk;Wvo]^T + [bq;bk;bvo]   (8192 x 1536, K=512)
//  A  : banded-Gram attention -> newx (8192 x 512)
//  LN1: x1 = LN(xb + newx)
//  G3 : h = gelu(x1 @ W1T^T + b1)       (8192 x 2048, K=512)
//  G4 : y = h @ W2T^T  (split-K=2 -> 2 bf16 partials)
//  LN2: out = LN(x1 + y0 + y1 + b2) -> fp32
//
// gemm (R8): 128x64 tile, 4 waves (wave 64x32, acc[4][2]), BK=32.
// 3 LDS buffers (36KB -> 4 blocks/CU), lookahead-2, counted s_waitcnt vmcnt(3)
// (never drains the just-issued stage; R4 showed counted-vmcnt gives ~20%
// better per-wave throughput — this keeps it WITHOUT R4's occupancy loss).
// Granule-permuted LDS (conflict-free, verified 0 conflicts R4/R7),
// XCD-chunked block swizzle. No setprio (m190: negative on lockstep GEMM).
// ---------------------------------------------------------------------------

typedef unsigned short u16;
typedef __attribute__((ext_vector_type(8))) short short8;   // 8 bf16
typedef __attribute__((ext_vector_type(4))) float floatx4;  // MFMA acc

#define DEV static __device__ __forceinline__

DEV float b2f(u16 u) {
  union { unsigned int i; float f; } x; x.i = ((unsigned int)u) << 16; return x.f;
}
DEV u16 f2b(float f) {  // round-to-nearest-even
  union { float f; unsigned int i; } x; x.f = f;
  unsigned int u = x.i + 0x7fffu + ((x.i >> 16) & 1u);
  return (u16)(u >> 16);
}

#define AS1 __attribute__((address_space(1)))
#define AS3 __attribute__((address_space(3)))
DEV void gload_lds16(const void* g, void* l) {
  __builtin_amdgcn_global_load_lds((const AS1 void*)g, (AS3 void*)l, 16, 0, 0);
}

// ---------------------------------------------------------------------------
// Fused weight prep: transposes (fp32 RxC -> bf16 CxR) for Wq,Wk,Wo,W1,W2
// plus straight f2b copy of Wv.
// blocks: [0,256) Wq | [256,512) Wk | [512,768) Wo | [768,1792) W1
//         [1792,2816) W2 | [2816,3072) Wv copy
// ---------------------------------------------------------------------------
__global__ __launch_bounds__(256) void prep_weights(
    const float* __restrict__ Wq, const float* __restrict__ Wk,
    const float* __restrict__ Wo, const float* __restrict__ W1,
    const float* __restrict__ W2, const float* __restrict__ Wv,
    u16* __restrict__ WqkvT, u16* __restrict__ WoT,
    u16* __restrict__ W1T, u16* __restrict__ W2T, u16* __restrict__ Wvb) {
  const int bid = blockIdx.x;
  if (bid >= 2816) {  // Wv f2b copy (512x512)
    const int i = (bid - 2816) * 256 + threadIdx.x;
    float4 v = ((const float4*)Wv)[i];
    ushort4 o;
    o.x = f2b(v.x); o.y = f2b(v.y); o.z = f2b(v.z); o.w = f2b(v.w);
    ((ushort4*)Wvb)[i] = o;
    return;
  }
  const float* in; u16* out; int R, C, t;
  if (bid < 256)       { in = Wq; out = WqkvT;          R = 512;  C = 512;  t = bid; }
  else if (bid < 512)  { in = Wk; out = WqkvT + 262144; R = 512;  C = 512;  t = bid - 256; }
  else if (bid < 768)  { in = Wo; out = WoT;            R = 512;  C = 512;  t = bid - 512; }
  else if (bid < 1792) { in = W1; out = W1T;            R = 512;  C = 2048; t = bid - 768; }
  else                 { in = W2; out = W2T;            R = 2048; C = 512;  t = bid - 1792; }
  const int tpr = C >> 5;
  const int bc = (t % tpr) * 32, br = (t / tpr) * 32;
  __shared__ float tile[32][33];
  const int tx = threadIdx.x & 31, ty = threadIdx.x >> 5;
  #pragma unroll
  for (int i = 0; i < 32; i += 8)
    tile[ty + i][tx] = in[(size_t)(br + ty + i) * C + bc + tx];
  __syncthreads();
  #pragma unroll
  for (int i = 0; i < 32; i += 8)
    out[(size_t)(bc + ty + i) * R + br + tx] = f2b(tile[tx][ty + i]);
}

// bqkv[0:512)=bq, [512:1024)=bk, [1024:1536)=bvo=bv@Wo, [1536:2048)=0
__global__ __launch_bounds__(256) void bias_prep(
    const float* __restrict__ bq, const float* __restrict__ bk,
    const float* __restrict__ bv, const float* __restrict__ Wo,
    float* __restrict__ o) {
  const int i = blockIdx.x * 256 + threadIdx.x;
  if (i < 512) o[i] = bq[i];
  else if (i < 1024) o[i] = bk[i - 512];
  else if (i < 1536) {
    const int c = i - 1024;
    float s = 0.f;
    for (int j = 0; j < 512; ++j) s += bv[j] * Wo[(size_t)j * 512 + c];
    o[i] = s;
  } else if (i < 2048) o[i] = 0.f;
}

__global__ __launch_bounds__(256) void f2b_vec(
    const float* __restrict__ in, u16* __restrict__ out, int n4) {
  int i = blockIdx.x * 256 + threadIdx.x;
  if (i < n4) {
    float4 v = ((const float4*)in)[i];
    ushort4 o;
    o.x = f2b(v.x); o.y = f2b(v.y); o.z = f2b(v.z); o.w = f2b(v.w);
    ((ushort4*)out)[i] = o;
  }
}

// ---------------------------------------------------------------------------
// High-occupancy bf16 MFMA GEMM with counted-vmcnt 3-buffer pipeline.
// C = A[M][lda] @ BT[N][lda]^T (+ bias)
// EPI: 0=bias->bf16, 1=bias+gelu->bf16, 2=raw bf16 partial (split-K via z)
// BM=128, BN=64, BK=32; 256 thr = 4 waves (wr=w&1, wc=w>>1), wave 64x32.
// LDS 3 x (A 8KB | B 4KB) = 36KB -> 4 blocks/CU.
// Buffer rotation: read t%3, in-flight write (t+2)%3, both distinct from
// each other and the next read — WAR-safe with the end-of-iter barrier.
// Steady-state wait: vmcnt(3) (= stage t+1 resident, stage t+2 in flight).
// ---------------------------------------------------------------------------
template<int EPI>
__global__ __launch_bounds__(256, 4) void gemm_bt(
    const u16* __restrict__ A, const u16* __restrict__ BT,
    const float* __restrict__ bias, u16* __restrict__ C, u16* __restrict__ C2,
    int M, int N, int lda, int kb) {
  __shared__ __align__(16) u16 As[3][4096];
  __shared__ __align__(16) u16 Bs[3][2048];
  const int tid = threadIdx.x;
  const int w = tid >> 6, l = tid & 63;
  const int l15 = l & 15, l4 = l >> 4;
  const int wr = w & 1, wc = w >> 1;

  // T1: XCD-chunked swizzle (guard nwg%8)
  const int gx = (int)gridDim.x, gy = (int)gridDim.y;
  int id = ((int)blockIdx.z * gy + (int)blockIdx.y) * gx + (int)blockIdx.x;
  const int nwg = gx * gy * (int)gridDim.z;
  if ((nwg & 7) == 0) { const int cpx = nwg >> 3; id = (id & 7) * cpx + (id >> 3); }
  const int bx = id % gx; const int r1 = id / gx;
  const int by = r1 % gy; const int bz = r1 / gy;
  const int bm = by * 128, bn = bx * 64;
  const int koff = bz * kb;

  // staging: thread -> (row0 = tid>>2, permuted source granule)
  const int row0 = tid >> 2;
  const int kc0 = ((((tid & 3) - ((tid >> 3) & 3)) & 3)) * 8;
  const u16* gA = A  + (size_t)(bm + row0) * lda + koff + kc0;
  const u16* gB = BT + (size_t)(bn + row0) * lda + koff + kc0;
  const size_t a1 = (size_t)64 * lda;      // A pass-1 row offset
  const int sd = w * 512 + l * 8;          // linear, wave-contiguous LDS dest

  // fragment read offsets: physical slot = (l4 + (row>>1)) & 3
  const int rg8 = ((l4 + ((l15 >> 1) & 3)) & 3) * 8;
  const int aBase = (wr * 64 + l15) * 32 + rg8;
  const int bBase = (wc * 32 + l15) * 32 + rg8;

  floatx4 acc[4][2] = {};
  const int nt = kb >> 5;

  auto stage = [&](int t, int buf) {
    const u16* a = gA + (size_t)t * 32;
    const u16* b = gB + (size_t)t * 32;
    gload_lds16(a,      &As[buf][sd]);
    gload_lds16(a + a1, &As[buf][2048 + sd]);
    gload_lds16(b,      &Bs[buf][sd]);
  };

  // prologue: stage 0 and 1; wait until stage 0 resident (3 of stage 1 in flight)
  stage(0, 0);
  stage(1, 1);
  asm volatile("s_waitcnt vmcnt(3)" ::: "memory");
  __builtin_amdgcn_s_barrier();
  asm volatile("" ::: "memory");

  int cur = 0;
  for (int t = 0; t < nt; ++t) {
    int sb = cur + 2; if (sb >= 3) sb -= 3;
    const bool pf = (t + 2 < nt);
    if (pf) stage(t + 2, sb);

    short8 af[4], bf[2];
    #pragma unroll
    for (int m = 0; m < 4; ++m) af[m] = *(const short8*)(&As[cur][aBase + m * 512]);
    #pragma unroll
    for (int n = 0; n < 2; ++n) bf[n] = *(const short8*)(&Bs[cur][bBase + n * 512]);
    #pragma unroll
    for (int m = 0; m < 4; ++m)
      #pragma unroll
      for (int n = 0; n < 2; ++n)
        acc[m][n] = __builtin_amdgcn_mfma_f32_16x16x32_bf16(af[m], bf[n], acc[m][n], 0, 0, 0);

    // counted drain: stage(t+1) resident, stage(t+2)'s 3 loads stay in flight
    if (pf) asm volatile("s_waitcnt vmcnt(3)" ::: "memory");
    else    asm volatile("s_waitcnt vmcnt(0)" ::: "memory");
    __builtin_amdgcn_s_barrier();
    asm volatile("" ::: "memory");

    cur = (cur == 2) ? 0 : cur + 1;
  }

  // ---- epilogue ----
  const int col0 = bn + wc * 32 + l15;
  if (EPI <= 1) {
    float bvv[2];
    #pragma unroll
    for (int n = 0; n < 2; ++n) bvv[n] = bias[col0 + n * 16];
    #pragma unroll
    for (int m = 0; m < 4; ++m) {
      #pragma unroll
      for (int ri = 0; ri < 4; ++ri) {
        const size_t row = (size_t)(bm + wr * 64 + m * 16 + l4 * 4 + ri);
        u16* cp = C + row * N + col0;
        #pragma unroll
        for (int n = 0; n < 2; ++n) {
          float vv = acc[m][n][ri] + bvv[n];
          if (EPI == 1) vv = 0.5f * vv * (1.0f + erff(vv * 0.70710678118654752f));
          cp[n * 16] = f2b(vv);
        }
      }
    }
  } else {
    u16* o = (bz == 0) ? C : C2;
    #pragma unroll
    for (int m = 0; m < 4; ++m) {
      #pragma unroll
      for (int ri = 0; ri < 4; ++ri) {
        const size_t row = (size_t)(bm + wr * 64 + m * 16 + l4 * 4 + ri);
        u16* cp = o + row * N + col0;
        #pragma unroll
        for (int n = 0; n < 2; ++n) cp[n * 16] = f2b(acc[m][n][ri]);
      }
    }
  }
}

// ---------------------------------------------------------------------------
// Banded-Gram attention. One block per (b, 32-pos chunk, head).
// ---------------------------------------------------------------------------
#define ATL 32
#define ART (ATL + 8)   // 40 staged rows

__global__ __launch_bounds__(256) void attn_band(
    const u16* __restrict__ QKV, const float* __restrict__ bqkv,
    const float* __restrict__ bo, u16* __restrict__ newx) {
  __shared__ __align__(16) u16 S3[3][ART][72];
  __shared__ float Gb[ART][18];
  __shared__ float Sm[ART][81];
  __shared__ float Wb[ATL][9];

  const int tid = threadIdx.x;
  const int bid = ((int)blockIdx.x & 7) * 256 + ((int)blockIdx.x >> 3);
  const int h = bid & 7;
  const int chunk = (bid >> 3) & 63;
  const int b = bid >> 9;
  const int l0 = chunk * ATL;

  for (int idx = tid; idx < ART * 24; idx += 256) {
    const int ti = idx / 24, c = idx % 24;
    const int slice = c >> 3, d8 = (c & 7) * 8;
    const int col = slice * 512 + h * 64 + d8;
    const int t = l0 - 4 + ti;
    short8 v;
    if ((unsigned)t < 2048u) {
      v = *(const short8*)(QKV + ((size_t)((b << 11) | t)) * 1536 + col);
    } else {
      #pragma unroll
      for (int j = 0; j < 8; ++j) v[j] = (short)f2b(bqkv[col + j]);
    }
    *(short8*)(&S3[slice][ti][d8]) = v;
  }
  __syncthreads();

  for (int task = tid; task < ART * 17; task += 256) {
    const int ti = task / 17, j = task % 17;
    const int ui = ti + j - 8;
    if ((unsigned)ui < (unsigned)ART) {
      float a = 0.f;
      #pragma unroll
      for (int d0 = 0; d0 < 64; d0 += 8) {
        short8 qv = *(const short8*)(&S3[0][ti][d0]);
        short8 kv = *(const short8*)(&S3[1][ui][d0]);
        #pragma unroll
        for (int jj = 0; jj < 8; ++jj) a += b2f((u16)qv[jj]) * b2f((u16)kv[jj]);
      }
      Gb[ti][j] = a * 0.125f;
    }
  }
  __syncthreads();

  for (int task = tid; task < ART * 9; task += 256) {
    const int ti = task / 9, qw = task % 9;
    const int li = ti - qw;
    if ((unsigned)li < (unsigned)ATL) {
      float m = -1e30f;
      #pragma unroll
      for (int kw = 0; kw < 9; ++kw) m = fmaxf(m, Gb[ti][kw - qw + 8]);
      float e[9], s = 0.f;
      #pragma unroll
      for (int kw = 0; kw < 9; ++kw) { e[kw] = expf(Gb[ti][kw - qw + 8] - m); s += e[kw]; }
      const float inv = 1.f / s;
      #pragma unroll
      for (int kw = 0; kw < 9; ++kw) Sm[ti][qw * 9 + kw] = e[kw] * inv;
    }
  }
  __syncthreads();

  for (int task = tid; task < ATL * 9; task += 256) {
    const int li = task / 9, kw = task % 9;
    float s = 0.f;
    #pragma unroll
    for (int qw = 0; qw < 9; ++qw) s += Sm[li + qw][qw * 9 + kw];
    Wb[li][kw] = s * (1.f / 9.f);
  }
  __syncthreads();

  {
    const int li = tid >> 3, d8 = (tid & 7) * 8;
    float w[9];
    #pragma unroll
    for (int kw = 0; kw < 9; ++kw) w[kw] = Wb[li][kw];
    float a[8] = {};
    #pragma unroll
    for (int kw = 0; kw < 9; ++kw) {
      short8 vv = *(const short8*)(&S3[2][li + kw][d8]);
      #pragma unroll
      for (int jj = 0; jj < 8; ++jj) a[jj] += w[kw] * b2f((u16)vv[jj]);
    }
    short8 o;
    #pragma unroll
    for (int jj = 0; jj < 8; ++jj) o[jj] = (short)f2b(a[jj] + bo[h * 64 + d8 + jj]);
    const int l = l0 + li;
    *(short8*)(newx + ((size_t)((b << 11) | l)) * 512 + h * 64 + d8) = o;
  }
}

// ---------------------------------------------------------------------------
// LayerNorm over D=512. One wave per row, 4 rows/block.
// MODE 0: v = a + b                  -> bf16 out
// MODE 1: v = a + b + c + bias[col]  -> fp32 out
// ---------------------------------------------------------------------------
template<int MODE>
__global__ __launch_bounds__(256) void ln_kernel(
    const u16* __restrict__ a, const u16* __restrict__ bsrc,
    const u16* __restrict__ csrc, const float* __restrict__ bias,
    const float* __restrict__ g, const float* __restrict__ be,
    u16* __restrict__ outb, float* __restrict__ outf) {
  const int wave = threadIdx.x >> 6, lane = threadIdx.x & 63;
  const size_t row = (size_t)blockIdx.x * 4 + wave;
  const size_t base = row * 512 + lane * 8;
  const int gi = lane * 8;
  float v[8];
  short8 a8 = *(const short8*)(a + base);
  short8 b8 = *(const short8*)(bsrc + base);
  #pragma unroll
  for (int j = 0; j < 8; ++j) v[j] = b2f((u16)a8[j]) + b2f((u16)b8[j]);
  if (MODE == 1) {
    short8 c8 = *(const short8*)(csrc + base);
    #pragma unroll
    for (int j = 0; j < 8; ++j) v[j] += b2f((u16)c8[j]) + bias[gi + j];
  }

  float s = 0.f;
  #pragma unroll
  for (int j = 0; j < 8; ++j) s += v[j];
  #pragma unroll
  for (int off = 32; off >= 1; off >>= 1) s += __shfl_xor(s, off, 64);
  const float mean = s * (1.f / 512.f);
  float sq = 0.f;
  #pragma unroll
  for (int j = 0; j < 8; ++j) { float d = v[j] - mean; sq += d * d; }
  #pragma unroll
  for (int off = 32; off >= 1; off >>= 1) sq += __shfl_xor(sq, off, 64);
  const float rs = rsqrtf(sq * (1.f / 512.f) + 1e-5f);

  if (MODE == 0) {
    short8 o;
    #pragma unroll
    for (int j = 0; j < 8; ++j)
      o[j] = (short)f2b((v[j] - mean) * rs * g[gi + j] + be[gi + j]);
    *(short8*)(outb + base) = o;
  } else {
    float4 o0, o1;
    o0.x = (v[0] - mean) * rs * g[gi + 0] + be[gi + 0];
    o0.y = (v[1] - mean) * rs * g[gi + 1] + be[gi + 1];
    o0.z = (v[2] - mean) * rs * g[gi + 2] + be[gi + 2];
    o0.w = (v[3] - mean) * rs * g[gi + 3] + be[gi + 3];
    o1.x = (v[4] - mean) * rs * g[gi + 4] + be[gi + 4];
    o1.y = (v[5] - mean) * rs * g[gi + 5] + be[gi + 5];
    o1.z = (v[6] - mean) * rs * g[gi + 6] + be[gi + 6];
    o1.w = (v[7] - mean) * rs * g[gi + 7] + be[gi + 7];
    *(float4*)(outf + base) = o0;
    *(float4*)(outf + base + 4) = o1;
  }
}

// ---------------------------------------------------------------------------
extern "C" void kernel_launch(void* const* d_in, const int* in_sizes, int n_in,
                              void* d_out, int out_size, void* d_ws, size_t ws_size,
                              hipStream_t stream) {
  const float* x   = (const float*)d_in[0];
  const float* Wq  = (const float*)d_in[1];
  const float* bq  = (const float*)d_in[2];
  const float* Wk  = (const float*)d_in[3];
  const float* bk  = (const float*)d_in[4];
  const float* Wv  = (const float*)d_in[5];
  const float* bv  = (const float*)d_in[6];
  const float* Wo  = (const float*)d_in[7];
  const float* bo  = (const float*)d_in[8];
  const float* W1  = (const float*)d_in[9];
  const float* b1  = (const float*)d_in[10];
  const float* W2  = (const float*)d_in[11];
  const float* b2  = (const float*)d_in[12];
  const float* g1  = (const float*)d_in[13];
  const float* be1 = (const float*)d_in[14];
  const float* g2  = (const float*)d_in[15];
  const float* be2 = (const float*)d_in[16];

  char* w = (char*)d_ws;
  u16*   xb    = (u16*)  (w + 0);           // 8 MB; reused as y-partial-1 after LN1
  u16*   WqkvT = (u16*)  (w + 8388608);     // [1536][512] bf16 (q,k,vo)
  u16*   WoT   = (u16*)  (w + 9961472);     // [512][512] bf16 Wo^T
  u16*   W1T   = (u16*)  (w + 10485760);    // [2048][512]
  u16*   W2T   = (u16*)  (w + 12582912);    // [512][2048]
  float* bqkv  = (float*)(w + 14680064);    // 2048 f32 (bq,bk,bvo,zeros)
  u16*   Wvb   = (u16*)  (w + 14688256);    // [512][512] bf16 row-major Wv
  u16*   QKV   = (u16*)  (w + 15212544);    // 8192x1536 bf16 (dead after attn)
  u16*   hbuf  = QKV;                       // 8192x2048 bf16 (aliases QKV)
  u16*   newx  = (u16*)  (w + 48766976);    // 8192x512 bf16; y-partial-0 after LN1
  u16*   x1b   = (u16*)  (w + 57155584);    // 8192x512 bf16
  u16*   WvoT  = WqkvT + 524288;            // V region of WqkvT = (Wv@Wo)^T
  u16*   yp0   = newx;                      // G4 split-K partial z=0
  u16*   yp1   = xb;                        // G4 split-K partial z=1

  // --- prep ---
  prep_weights<<<3072, 256, 0, stream>>>(Wq, Wk, Wo, W1, W2, Wv,
                                         WqkvT, WoT, W1T, W2T, Wvb);
  bias_prep<<<8, 256, 0, stream>>>(bq, bk, bv, Wo, bqkv);
  f2b_vec<<<4096, 256, 0, stream>>>(x, xb, 1048576);
  // --- WvoT = (Wv@Wo)^T via MFMA GEMM: C[n][k] = sum_j WoT[n][j]*Wvb[k][j] ---
  gemm_bt<0><<<dim3(8, 4, 1), 256, 0, stream>>>(WoT, Wvb, bqkv + 1536, WvoT, nullptr,
                                                512, 512, 512, 512);
  // --- G1: QKV'' ---
  gemm_bt<0><<<dim3(24, 64, 1), 256, 0, stream>>>(xb, WqkvT, bqkv, QKV, nullptr,
                                                  8192, 1536, 512, 512);
  // --- attention (banded Gram) -> newx ---
  attn_band<<<2048, 256, 0, stream>>>(QKV, bqkv, bo, newx);
  // --- LN1: x1 = LN(xb + newx) ---
  ln_kernel<0><<<2048, 256, 0, stream>>>(xb, newx, nullptr, nullptr, g1, be1, x1b, nullptr);
  // --- G3: h = gelu(x1 @ W1T^T + b1) ---
  gemm_bt<1><<<dim3(32, 64, 1), 256, 0, stream>>>(x1b, W1T, b1, hbuf, nullptr,
                                                  8192, 2048, 512, 512);
  // --- G4: y partials (split-K=2) ---
  gemm_bt<2><<<dim3(8, 64, 2), 256, 0, stream>>>(hbuf, W2T, nullptr, yp0, yp1,
                                                 8192, 512, 2048, 1024);
  // --- LN2 -> out ---
  ln_kernel<1><<<2048, 256, 0, stream>>>(x1b, yp0, yp1, b2, g2, be2, nullptr, (float*)d_out);
}